// Round 5
// baseline (322.795 us; speedup 1.0000x reference)
//
#include <hip/hip_runtime.h>
#include <math.h>

#define N_ROWS 65536
#define Q 4096
#define E 64
#define CT 64                 // codes staged per tile-step
#define NTS (Q / CT)          // 64 tile-steps
#define MARGIN 0.5f
#define CAP_LIST 8
#define KMASK 0xFFFFF000u

typedef short s8v __attribute__((ext_vector_type(8)));   // 8 bf16 (4 VGPRs)
typedef float f4v __attribute__((ext_vector_type(4)));   // 4 fp32 acc

// ---------- exact-arithmetic helpers (validated absmax=0 rounds 1-4) ----------
__device__ __forceinline__ float pairwise_sq_sum64(const float* v) {
#pragma clang fp contract(off)
  float r[8];
#pragma unroll
  for (int j = 0; j < 8; ++j) r[j] = v[j] * v[j];
#pragma unroll
  for (int i = 8; i < 64; i += 8) {
#pragma unroll
    for (int j = 0; j < 8; ++j) {
      float p = v[i + j] * v[i + j];
      r[j] = r[j] + p;
    }
  }
  return ((r[0] + r[1]) + (r[2] + r[3])) + ((r[4] + r[5]) + (r[6] + r[7]));
}

__device__ __forceinline__ void load_row64(const float* __restrict__ src,
                                           float* dst) {
  const float4* p = (const float4*)src;
#pragma unroll
  for (int k4 = 0; k4 < 16; ++k4) {
    const float4 t = p[k4];
    dst[4 * k4 + 0] = t.x;
    dst[4 * k4 + 1] = t.y;
    dst[4 * k4 + 2] = t.z;
    dst[4 * k4 + 3] = t.w;
  }
}

// exact distance, reference-bitwise: sequential fmaf dot, RN(hsq+wsq), fmaf(-2,...)
__device__ __forceinline__ float exact_dist(const float* hv, float hs,
                                            const float* __restrict__ w,
                                            float wsqc, int c) {
  const float* wr = w + (size_t)c * E;
  float dot = 0.f;
#pragma unroll
  for (int k = 0; k < E; ++k) dot = fmaf(wr[k], hv[k], dot);
  return fmaf(-2.f, dot, hs + wsqc);
}

__device__ __forceinline__ unsigned short bf16_rn(float f) {
  unsigned int u = __float_as_uint(f);
  u += 0x7FFFu + ((u >> 16) & 1u);
  return (unsigned short)(u >> 16);
}
__device__ __forceinline__ float bf16_to_f(unsigned short s) {
  return __uint_as_float(((unsigned int)s) << 16);
}

// ---------- prep: wsq + bf16 hi/lo of w in staged (frag-order) layout ----------
__global__ __launch_bounds__(256) void prep_w(const float* __restrict__ w,
                                              float* __restrict__ wsq,
                                              short* __restrict__ whiS,
                                              short* __restrict__ wloS,
                                              int* __restrict__ ovfCnt) {
  const int q = blockIdx.x * 256 + threadIdx.x;
  if (q == 0) *ovfCnt = 0;
  float v[E];
  load_row64(w + (size_t)q * E, v);
  wsq[q] = pairwise_sq_sum64(v);
  const int T = q >> 6, code_in = q & 63;
#pragma unroll
  for (int ch = 0; ch < 8; ++ch) {
    s8v hi, lo;
#pragma unroll
    for (int j = 0; j < 8; ++j) {
      const float f = v[ch * 8 + j];
      const unsigned short h = bf16_rn(f);
      const float resid = f - bf16_to_f(h);
      hi[j] = (short)h;
      lo[j] = (short)bf16_rn(resid);
    }
    const size_t base = (size_t)T * 4096 + ((size_t)(ch * 64 + code_in)) * 8;
    *(s8v*)&whiS[base] = hi;
    *(s8v*)&wloS[base] = lo;
  }
}

__global__ __launch_bounds__(256) void prep_x(const float* __restrict__ x,
                                              float* __restrict__ hsq) {
  const int n = blockIdx.x * 256 + threadIdx.x;
  float v[E];
  load_row64(x + (size_t)n * E, v);
  hsq[n] = pairwise_sq_sum64(v);
}

// ---------- main: MFMA screen + branchless packed top-2 + exact recheck ------
__global__ __launch_bounds__(256, 2) void dist_kernel(
    const float* __restrict__ x, const short* __restrict__ whiS,
    const short* __restrict__ wloS, const float* __restrict__ wsq,
    const float* __restrict__ hsq, const float* __restrict__ w,
    float* __restrict__ out, int* __restrict__ ovfCnt,
    int* __restrict__ ovfRows) {
  __shared__ short BsHi[CT * 64];    // 8 KB
  __shared__ short BsLo[CT * 64];    // 8 KB
  __shared__ float WsS[CT];
  __shared__ int cnt[128];
  __shared__ int flagS[128];
  __shared__ int lists[128][CAP_LIST];
  __shared__ int bestRow[128];

  const int tid = threadIdx.x;
  const int wv = tid >> 6;
  const int lane = tid & 63;
  const int n = lane & 15;
  const int quad = lane >> 4;
  const int rowBase = blockIdx.x * 128;

  if (tid < 128) {
    cnt[tid] = 0;
    flagS[tid] = 0;
  }

  // ---- A-frags: a = -2x, split hi/lo, built once ----
  s8v ahi[2][2], alo[2][2];  // [rowtile][ks]
#pragma unroll
  for (int rt = 0; rt < 2; ++rt) {
#pragma unroll
    for (int ks = 0; ks < 2; ++ks) {
      const int gRow = rowBase + wv * 32 + rt * 16 + n;
      const float* xp = x + (size_t)gRow * E + ks * 32 + quad * 8;
      const float4 v0 = ((const float4*)xp)[0];
      const float4 v1 = ((const float4*)xp)[1];
      float vals[8] = {v0.x, v0.y, v0.z, v0.w, v1.x, v1.y, v1.z, v1.w};
      s8v hi, lo;
#pragma unroll
      for (int j = 0; j < 8; ++j) {
        const float a = -2.f * vals[j];
        const unsigned short h = bf16_rn(a);
        hi[j] = (short)h;
        lo[j] = (short)bf16_rn(a - bf16_to_f(h));
      }
      ahi[rt][ks] = hi;
      alo[rt][ks] = lo;
    }
  }

  // hsq + 4.0 offset folded into C-init (keeps packed floats positive)
  float hsqv4[2][4];
#pragma unroll
  for (int rt = 0; rt < 2; ++rt)
#pragma unroll
    for (int r = 0; r < 4; ++r)
      hsqv4[rt][r] = hsq[rowBase + wv * 32 + rt * 16 + quad * 4 + r] + 4.0f;

  // branchless packed top-2 per (rowtile, r): key = (bits(d+4)&KMASK)|code
  unsigned int m0[2][4], m1[2][4];
#pragma unroll
  for (int rt = 0; rt < 2; ++rt)
#pragma unroll
    for (int r = 0; r < 4; ++r) {
      m0[rt][r] = 0xFFFFFFFFu;
      m1[rt][r] = 0xFFFFFFFFu;
    }

#pragma unroll 1
  for (int ts = 0; ts < NTS; ++ts) {
    __syncthreads();
    {
      const int4* gh = (const int4*)(whiS + (size_t)ts * 4096);
      const int4* gl = (const int4*)(wloS + (size_t)ts * 4096);
      ((int4*)BsHi)[tid] = gh[tid];
      ((int4*)BsHi)[tid + 256] = gh[tid + 256];
      ((int4*)BsLo)[tid] = gl[tid];
      ((int4*)BsLo)[tid + 256] = gl[tid + 256];
      if (tid < CT) WsS[tid] = wsq[ts * CT + tid];
    }
    __syncthreads();

#pragma unroll
    for (int ct = 0; ct < 4; ++ct) {
      const s8v bhi0 = *(const s8v*)&BsHi[(size_t)((0 * 4 + quad) * 64 + ct * 16 + n) * 8];
      const s8v bhi1 = *(const s8v*)&BsHi[(size_t)((1 * 4 + quad) * 64 + ct * 16 + n) * 8];
      const s8v blo0 = *(const s8v*)&BsLo[(size_t)((0 * 4 + quad) * 64 + ct * 16 + n) * 8];
      const s8v blo1 = *(const s8v*)&BsLo[(size_t)((1 * 4 + quad) * 64 + ct * 16 + n) * 8];
      const float wsn = WsS[ct * 16 + n];
      const unsigned int codeT = (unsigned int)(ts * CT + ct * 16 + n);
#pragma unroll
      for (int rt = 0; rt < 2; ++rt) {
        f4v acc;
        acc[0] = hsqv4[rt][0] + wsn;
        acc[1] = hsqv4[rt][1] + wsn;
        acc[2] = hsqv4[rt][2] + wsn;
        acc[3] = hsqv4[rt][3] + wsn;
        acc = __builtin_amdgcn_mfma_f32_16x16x32_bf16(alo[rt][0], bhi0, acc, 0, 0, 0);
        acc = __builtin_amdgcn_mfma_f32_16x16x32_bf16(ahi[rt][0], blo0, acc, 0, 0, 0);
        acc = __builtin_amdgcn_mfma_f32_16x16x32_bf16(ahi[rt][0], bhi0, acc, 0, 0, 0);
        acc = __builtin_amdgcn_mfma_f32_16x16x32_bf16(alo[rt][1], bhi1, acc, 0, 0, 0);
        acc = __builtin_amdgcn_mfma_f32_16x16x32_bf16(ahi[rt][1], blo1, acc, 0, 0, 0);
        acc = __builtin_amdgcn_mfma_f32_16x16x32_bf16(ahi[rt][1], bhi1, acc, 0, 0, 0);
#pragma unroll
        for (int r = 0; r < 4; ++r) {
          const unsigned int key =
              (__float_as_uint(acc[r]) & KMASK) | codeT;      // v_and_or_b32
          const unsigned int lo = m0[rt][r] < key ? m0[rt][r] : key;  // v_min
          const unsigned int hi = m0[rt][r] > key ? m0[rt][r] : key;  // v_max
          m0[rt][r] = lo;
          m1[rt][r] = m1[rt][r] < hi ? m1[rt][r] : hi;                // v_min
        }
      }
    }
  }

  // ---- candidate collection: rowmin via 16-lane butterfly, push <= thr ----
  __syncthreads();
#pragma unroll
  for (int rt = 0; rt < 2; ++rt) {
#pragma unroll
    for (int r = 0; r < 4; ++r) {
      unsigned int km = m0[rt][r];
#pragma unroll
      for (int off = 1; off < 16; off <<= 1) {
        const unsigned int o = __shfl_xor(km, off, 64);
        km = o < km ? o : km;
      }
      const float thr = __uint_as_float(km & KMASK) + MARGIN;
      const int row_l = wv * 32 + rt * 16 + quad * 4 + r;
      const float f0 = __uint_as_float(m0[rt][r] & KMASK);
      const float f1 = __uint_as_float(m1[rt][r] & KMASK);
      if (f0 <= thr) {
        const int pos = atomicAdd(&cnt[row_l], 1);
        if (pos < CAP_LIST) lists[row_l][pos] = (int)(m0[rt][r] & 0xFFFu);
        else flagS[row_l] = 1;
      }
      if (f1 <= thr) flagS[row_l] = 1;  // a dropped 3rd could be in-margin
    }
  }
  __syncthreads();

  // ---- exact recheck (reference-bitwise) over candidates ----
  if (tid < 128) {
    const int g = rowBase + tid;
    if (flagS[tid]) {
      const int pos = atomicAdd(ovfCnt, 1);
      ovfRows[pos] = g;
    } else {
      float hv[E];
      load_row64(x + (size_t)g * E, hv);
      const float hs = hsq[g];
      const int nc = cnt[tid] < CAP_LIST ? cnt[tid] : CAP_LIST;
      float bd = INFINITY;
      int bi = 0x7FFFFFFF;
      for (int i = 0; i < nc; ++i) {
        const int c = lists[tid][i];
        const float d = exact_dist(hv, hs, w, wsq[c], c);
        if (d < bd || (d == bd && c < bi)) { bd = d; bi = c; }
      }
      bestRow[tid] = bi;
      out[(size_t)N_ROWS * E + g] = (float)bi;
    }
  }
  __syncthreads();
  // ---- gather codeword ----
  {
    const int r = tid >> 1, h = tid & 1;
    if (!flagS[r]) {
      const int bi = bestRow[r];
      const float4* src = (const float4*)(w + (size_t)bi * E + h * 32);
      float4* dst = (float4*)(out + (size_t)(rowBase + r) * E + h * 32);
#pragma unroll
      for (int i = 0; i < 8; ++i) dst[i] = src[i];
    }
  }
}

// ---------- fallback: full exact scan, one wave per overflow row ----------
__global__ __launch_bounds__(64) void fallback_kernel(
    const float* __restrict__ x, const float* __restrict__ w,
    const float* __restrict__ wsq, const float* __restrict__ hsq,
    float* __restrict__ out, const int* __restrict__ ovfCnt,
    const int* __restrict__ ovfRows) {
  const int novf = *ovfCnt;
  const int lane = threadIdx.x;
  for (int i = blockIdx.x; i < novf; i += gridDim.x) {
    const int row = ovfRows[i];
    float hv[E];
    load_row64(x + (size_t)row * E, hv);
    const float hs = hsq[row];
    float bd = INFINITY;
    int bi = 0x7FFFFFFF;
    for (int c0 = 0; c0 < 64; ++c0) {
      const int c = c0 * 64 + lane;
      const float d = exact_dist(hv, hs, w, wsq[c], c);
      if (d < bd || (d == bd && c < bi)) { bd = d; bi = c; }
    }
#pragma unroll
    for (int off = 1; off < 64; off <<= 1) {
      const float od = __shfl_xor(bd, off, 64);
      const int oi = __shfl_xor(bi, off, 64);
      if (od < bd || (od == bd && oi < bi)) { bd = od; bi = oi; }
    }
    if (lane == 0) out[(size_t)N_ROWS * E + row] = (float)bi;
    out[(size_t)row * E + lane] = w[(size_t)bi * E + lane];
  }
}

extern "C" void kernel_launch(void* const* d_in, const int* in_sizes, int n_in,
                              void* d_out, int out_size, void* d_ws,
                              size_t ws_size, hipStream_t stream) {
  const float* x = (const float*)d_in[0];
  const float* w = (const float*)d_in[1];
  float* out = (float*)d_out;

  float* wsq = (float*)d_ws;
  float* hsq = wsq + Q;
  short* whiS = (short*)(hsq + N_ROWS);
  short* wloS = whiS + (size_t)Q * E;
  int* ovfCnt = (int*)(wloS + (size_t)Q * E);
  int* ovfRows = ovfCnt + 4;

  prep_w<<<Q / 256, 256, 0, stream>>>(w, wsq, whiS, wloS, ovfCnt);
  prep_x<<<N_ROWS / 256, 256, 0, stream>>>(x, hsq);
  dist_kernel<<<N_ROWS / 128, 256, 0, stream>>>(x, whiS, wloS, wsq, hsq, w, out,
                                                ovfCnt, ovfRows);
  fallback_kernel<<<256, 64, 0, stream>>>(x, w, wsq, hsq, out, ovfCnt, ovfRows);
}

// Round 6
// 309.661 us; speedup vs baseline: 1.0424x; 1.0424x over previous
//
#include <hip/hip_runtime.h>
#include <math.h>

#define N_ROWS 65536
#define Q 4096
#define E 64
#define CT 64                 // codes staged per tile-step
#define NTS (Q / CT)          // 64 tile-steps
#define MARGIN 0.25f
#define CAP_LIST 8
#define KMASK 0xFFFFF000u

typedef short s8v __attribute__((ext_vector_type(8)));   // 8 bf16 (4 VGPRs)
typedef float f4v __attribute__((ext_vector_type(4)));   // 4 fp32 acc

// ---------- exact-arithmetic helpers (validated absmax=0 rounds 1-5) ----------
__device__ __forceinline__ float pairwise_sq_sum64(const float* v) {
#pragma clang fp contract(off)
  float r[8];
#pragma unroll
  for (int j = 0; j < 8; ++j) r[j] = v[j] * v[j];
#pragma unroll
  for (int i = 8; i < 64; i += 8) {
#pragma unroll
    for (int j = 0; j < 8; ++j) {
      float p = v[i + j] * v[i + j];
      r[j] = r[j] + p;
    }
  }
  return ((r[0] + r[1]) + (r[2] + r[3])) + ((r[4] + r[5]) + (r[6] + r[7]));
}

__device__ __forceinline__ void load_row64(const float* __restrict__ src,
                                           float* dst) {
  const float4* p = (const float4*)src;
#pragma unroll
  for (int k4 = 0; k4 < 16; ++k4) {
    const float4 t = p[k4];
    dst[4 * k4 + 0] = t.x;
    dst[4 * k4 + 1] = t.y;
    dst[4 * k4 + 2] = t.z;
    dst[4 * k4 + 3] = t.w;
  }
}

// exact distance, reference-bitwise: float4 loads into regs, then sequential
// fmaf k ascending, RN(hsq+wsq), fmaf(-2,...)
__device__ __forceinline__ float exact_dist(const float* hv, float hs,
                                            const float* __restrict__ w,
                                            float wsqc, int c) {
  float wr[E];
  load_row64(w + (size_t)c * E, wr);
  float dot = 0.f;
#pragma unroll
  for (int k = 0; k < E; ++k) dot = fmaf(wr[k], hv[k], dot);
  return fmaf(-2.f, dot, hs + wsqc);
}

__device__ __forceinline__ unsigned short bf16_rn(float f) {
  unsigned int u = __float_as_uint(f);
  u += 0x7FFFu + ((u >> 16) & 1u);
  return (unsigned short)(u >> 16);
}
__device__ __forceinline__ float bf16_to_f(unsigned short s) {
  return __uint_as_float(((unsigned int)s) << 16);
}

// ---------- fused prep: blocks 0..15 -> w path, 16..271 -> x path ----------
__global__ __launch_bounds__(256) void prep_kernel(
    const float* __restrict__ w, const float* __restrict__ x,
    float* __restrict__ wsq, float* __restrict__ hsq,
    short* __restrict__ whiS, short* __restrict__ wloS,
    int* __restrict__ ovfCnt) {
  if (blockIdx.x < 16) {
    const int q = blockIdx.x * 256 + threadIdx.x;
    if (q == 0) *ovfCnt = 0;
    float v[E];
    load_row64(w + (size_t)q * E, v);
    wsq[q] = pairwise_sq_sum64(v);
    const int T = q >> 6, code_in = q & 63;
#pragma unroll
    for (int ch = 0; ch < 8; ++ch) {
      s8v hi, lo;
#pragma unroll
      for (int j = 0; j < 8; ++j) {
        const float f = v[ch * 8 + j];
        const unsigned short h = bf16_rn(f);
        const float resid = f - bf16_to_f(h);
        hi[j] = (short)h;
        lo[j] = (short)bf16_rn(resid);
      }
      const size_t base = (size_t)T * 4096 + ((size_t)(ch * 64 + code_in)) * 8;
      *(s8v*)&whiS[base] = hi;
      *(s8v*)&wloS[base] = lo;
    }
  } else {
    const int n = (blockIdx.x - 16) * 256 + threadIdx.x;
    float v[E];
    load_row64(x + (size_t)n * E, v);
    hsq[n] = pairwise_sq_sum64(v);
  }
}

// ---------- main: MFMA screen + branchless packed top-2 + exact recheck ------
__global__ __launch_bounds__(256, 2) void dist_kernel(
    const float* __restrict__ x, const short* __restrict__ whiS,
    const short* __restrict__ wloS, const float* __restrict__ wsq,
    const float* __restrict__ hsq, const float* __restrict__ w,
    float* __restrict__ out, int* __restrict__ ovfCnt,
    int* __restrict__ ovfRows) {
  __shared__ short BsHi[CT * 64];    // 8 KB
  __shared__ short BsLo[CT * 64];    // 8 KB
  __shared__ float WsS[CT];
  __shared__ int cnt[128];
  __shared__ int flagS[128];
  __shared__ int lists[128][CAP_LIST];
  __shared__ int bestRow[128];

  const int tid = threadIdx.x;
  const int wv = tid >> 6;
  const int lane = tid & 63;
  const int n = lane & 15;
  const int quad = lane >> 4;
  const int rowBase = blockIdx.x * 128;

  if (tid < 128) {
    cnt[tid] = 0;
    flagS[tid] = 0;
  }

  // ---- A-frags: a = -2x, split hi/lo, built once ----
  s8v ahi[2][2], alo[2][2];  // [rowtile][ks]
#pragma unroll
  for (int rt = 0; rt < 2; ++rt) {
#pragma unroll
    for (int ks = 0; ks < 2; ++ks) {
      const int gRow = rowBase + wv * 32 + rt * 16 + n;
      const float* xp = x + (size_t)gRow * E + ks * 32 + quad * 8;
      const float4 v0 = ((const float4*)xp)[0];
      const float4 v1 = ((const float4*)xp)[1];
      float vals[8] = {v0.x, v0.y, v0.z, v0.w, v1.x, v1.y, v1.z, v1.w};
      s8v hi, lo;
#pragma unroll
      for (int j = 0; j < 8; ++j) {
        const float a = -2.f * vals[j];
        const unsigned short h = bf16_rn(a);
        hi[j] = (short)h;
        lo[j] = (short)bf16_rn(a - bf16_to_f(h));
      }
      ahi[rt][ks] = hi;
      alo[rt][ks] = lo;
    }
  }

  // hsq + 4.0 offset folded into C-init (keeps packed floats positive)
  float hsqv4[2][4];
#pragma unroll
  for (int rt = 0; rt < 2; ++rt)
#pragma unroll
    for (int r = 0; r < 4; ++r)
      hsqv4[rt][r] = hsq[rowBase + wv * 32 + rt * 16 + quad * 4 + r] + 4.0f;

  // branchless packed top-2 per (rowtile, r): key = (bits(d+4)&KMASK)|code
  unsigned int m0[2][4], m1[2][4];
#pragma unroll
  for (int rt = 0; rt < 2; ++rt)
#pragma unroll
    for (int r = 0; r < 4; ++r) {
      m0[rt][r] = 0xFFFFFFFFu;
      m1[rt][r] = 0xFFFFFFFFu;
    }

#pragma unroll 1
  for (int ts = 0; ts < NTS; ++ts) {
    __syncthreads();
    {
      const int4* gh = (const int4*)(whiS + (size_t)ts * 4096);
      const int4* gl = (const int4*)(wloS + (size_t)ts * 4096);
      ((int4*)BsHi)[tid] = gh[tid];
      ((int4*)BsHi)[tid + 256] = gh[tid + 256];
      ((int4*)BsLo)[tid] = gl[tid];
      ((int4*)BsLo)[tid + 256] = gl[tid + 256];
      if (tid < CT) WsS[tid] = wsq[ts * CT + tid];
    }
    __syncthreads();

#pragma unroll
    for (int ct = 0; ct < 4; ++ct) {
      const s8v bhi0 = *(const s8v*)&BsHi[(size_t)((0 * 4 + quad) * 64 + ct * 16 + n) * 8];
      const s8v bhi1 = *(const s8v*)&BsHi[(size_t)((1 * 4 + quad) * 64 + ct * 16 + n) * 8];
      const s8v blo0 = *(const s8v*)&BsLo[(size_t)((0 * 4 + quad) * 64 + ct * 16 + n) * 8];
      const s8v blo1 = *(const s8v*)&BsLo[(size_t)((1 * 4 + quad) * 64 + ct * 16 + n) * 8];
      const float wsn = WsS[ct * 16 + n];
      const unsigned int codeT = (unsigned int)(ts * CT + ct * 16 + n);
#pragma unroll
      for (int rt = 0; rt < 2; ++rt) {
        f4v acc;
        acc[0] = hsqv4[rt][0] + wsn;
        acc[1] = hsqv4[rt][1] + wsn;
        acc[2] = hsqv4[rt][2] + wsn;
        acc[3] = hsqv4[rt][3] + wsn;
        acc = __builtin_amdgcn_mfma_f32_16x16x32_bf16(alo[rt][0], bhi0, acc, 0, 0, 0);
        acc = __builtin_amdgcn_mfma_f32_16x16x32_bf16(ahi[rt][0], blo0, acc, 0, 0, 0);
        acc = __builtin_amdgcn_mfma_f32_16x16x32_bf16(ahi[rt][0], bhi0, acc, 0, 0, 0);
        acc = __builtin_amdgcn_mfma_f32_16x16x32_bf16(alo[rt][1], bhi1, acc, 0, 0, 0);
        acc = __builtin_amdgcn_mfma_f32_16x16x32_bf16(ahi[rt][1], blo1, acc, 0, 0, 0);
        acc = __builtin_amdgcn_mfma_f32_16x16x32_bf16(ahi[rt][1], bhi1, acc, 0, 0, 0);
#pragma unroll
        for (int r = 0; r < 4; ++r) {
          const unsigned int key =
              (__float_as_uint(acc[r]) & KMASK) | codeT;      // v_and_or_b32
          const unsigned int lo = m0[rt][r] < key ? m0[rt][r] : key;  // v_min
          const unsigned int hi = m0[rt][r] > key ? m0[rt][r] : key;  // v_max
          m0[rt][r] = lo;
          m1[rt][r] = m1[rt][r] < hi ? m1[rt][r] : hi;                // v_min
        }
      }
    }
  }

  // ---- candidate collection: rowmin via 16-lane butterfly, push <= thr ----
  __syncthreads();
#pragma unroll
  for (int rt = 0; rt < 2; ++rt) {
#pragma unroll
    for (int r = 0; r < 4; ++r) {
      unsigned int km = m0[rt][r];
#pragma unroll
      for (int off = 1; off < 16; off <<= 1) {
        const unsigned int o = __shfl_xor(km, off, 64);
        km = o < km ? o : km;
      }
      const float thr = __uint_as_float(km & KMASK) + MARGIN;
      const int row_l = wv * 32 + rt * 16 + quad * 4 + r;
      const float f0 = __uint_as_float(m0[rt][r] & KMASK);
      const float f1 = __uint_as_float(m1[rt][r] & KMASK);
      if (f0 <= thr) {
        const int pos = atomicAdd(&cnt[row_l], 1);
        if (pos < CAP_LIST) lists[row_l][pos] = (int)(m0[rt][r] & 0xFFFu);
        else flagS[row_l] = 1;
      }
      if (f1 <= thr) flagS[row_l] = 1;  // a dropped 3rd could be in-margin
    }
  }
  __syncthreads();

  // ---- exact recheck (reference-bitwise) over candidates ----
  if (tid < 128) {
    const int g = rowBase + tid;
    if (flagS[tid]) {
      const int pos = atomicAdd(ovfCnt, 1);
      ovfRows[pos] = g;
    } else {
      float hv[E];
      load_row64(x + (size_t)g * E, hv);
      const float hs = hsq[g];
      const int nc = cnt[tid] < CAP_LIST ? cnt[tid] : CAP_LIST;
      float bd = INFINITY;
      int bi = 0x7FFFFFFF;
      for (int i = 0; i < nc; ++i) {
        const int c = lists[tid][i];
        const float d = exact_dist(hv, hs, w, wsq[c], c);
        if (d < bd || (d == bd && c < bi)) { bd = d; bi = c; }
      }
      bestRow[tid] = bi;
      out[(size_t)N_ROWS * E + g] = (float)bi;
    }
  }
  __syncthreads();
  // ---- gather codeword ----
  {
    const int r = tid >> 1, h = tid & 1;
    if (!flagS[r]) {
      const int bi = bestRow[r];
      const float4* src = (const float4*)(w + (size_t)bi * E + h * 32);
      float4* dst = (float4*)(out + (size_t)(rowBase + r) * E + h * 32);
#pragma unroll
      for (int i = 0; i < 8; ++i) dst[i] = src[i];
    }
  }
}

// ---------- fallback: full exact scan, 1 wave/row, 4096 waves grid-stride ----
__global__ __launch_bounds__(256) void fallback_kernel(
    const float* __restrict__ x, const float* __restrict__ w,
    const float* __restrict__ wsq, const float* __restrict__ hsq,
    float* __restrict__ out, const int* __restrict__ ovfCnt,
    const int* __restrict__ ovfRows) {
  const int novf = *ovfCnt;
  const int lane = threadIdx.x & 63;
  const int gw = blockIdx.x * 4 + (threadIdx.x >> 6);  // global wave id, 4096
  for (int i = gw; i < novf; i += 4096) {
    const int row = ovfRows[i];
    float hv[E];
    load_row64(x + (size_t)row * E, hv);
    const float hs = hsq[row];
    float bd = INFINITY;
    int bi = 0x7FFFFFFF;
    for (int c0 = 0; c0 < 64; ++c0) {
      const int c = c0 * 64 + lane;
      const float d = exact_dist(hv, hs, w, wsq[c], c);
      if (d < bd || (d == bd && c < bi)) { bd = d; bi = c; }
    }
#pragma unroll
    for (int off = 1; off < 64; off <<= 1) {
      const float od = __shfl_xor(bd, off, 64);
      const int oi = __shfl_xor(bi, off, 64);
      if (od < bd || (od == bd && oi < bi)) { bd = od; bi = oi; }
    }
    if (lane == 0) out[(size_t)N_ROWS * E + row] = (float)bi;
    out[(size_t)row * E + lane] = w[(size_t)bi * E + lane];
  }
}

extern "C" void kernel_launch(void* const* d_in, const int* in_sizes, int n_in,
                              void* d_out, int out_size, void* d_ws,
                              size_t ws_size, hipStream_t stream) {
  const float* x = (const float*)d_in[0];
  const float* w = (const float*)d_in[1];
  float* out = (float*)d_out;

  float* wsq = (float*)d_ws;
  float* hsq = wsq + Q;
  short* whiS = (short*)(hsq + N_ROWS);
  short* wloS = whiS + (size_t)Q * E;
  int* ovfCnt = (int*)(wloS + (size_t)Q * E);
  int* ovfRows = ovfCnt + 4;

  prep_kernel<<<272, 256, 0, stream>>>(w, x, wsq, hsq, whiS, wloS, ovfCnt);
  dist_kernel<<<N_ROWS / 128, 256, 0, stream>>>(x, whiS, wloS, wsq, hsq, w, out,
                                                ovfCnt, ovfRows);
  fallback_kernel<<<1024, 256, 0, stream>>>(x, w, wsq, hsq, out, ovfCnt,
                                            ovfRows);
}

// Round 7
// 302.793 us; speedup vs baseline: 1.0661x; 1.0227x over previous
//
#include <hip/hip_runtime.h>
#include <math.h>

#define N_ROWS 65536
#define Q 4096
#define E 64
#define CT 64                 // codes staged per tile-step
#define NTS (Q / CT)          // 64 tile-steps
#define MARGIN 0.25f
#define CAP_LIST 8
#define KMASK 0xFFFFF000u

typedef short s8v __attribute__((ext_vector_type(8)));   // 8 bf16 (4 VGPRs)
typedef float f4v __attribute__((ext_vector_type(4)));   // 4 fp32 acc

// ---------- exact-arithmetic helpers (validated absmax=0 rounds 1-6) ----------
__device__ __forceinline__ float pairwise_sq_sum64(const float* v) {
#pragma clang fp contract(off)
  float r[8];
#pragma unroll
  for (int j = 0; j < 8; ++j) r[j] = v[j] * v[j];
#pragma unroll
  for (int i = 8; i < 64; i += 8) {
#pragma unroll
    for (int j = 0; j < 8; ++j) {
      float p = v[i + j] * v[i + j];
      r[j] = r[j] + p;
    }
  }
  return ((r[0] + r[1]) + (r[2] + r[3])) + ((r[4] + r[5]) + (r[6] + r[7]));
}

__device__ __forceinline__ void load_row64(const float* __restrict__ src,
                                           float* dst) {
  const float4* p = (const float4*)src;
#pragma unroll
  for (int k4 = 0; k4 < 16; ++k4) {
    const float4 t = p[k4];
    dst[4 * k4 + 0] = t.x;
    dst[4 * k4 + 1] = t.y;
    dst[4 * k4 + 2] = t.z;
    dst[4 * k4 + 3] = t.w;
  }
}

// exact distance, reference-bitwise (round-5 form: direct pointer reads, no
// local array): sequential fmaf k ascending, RN(hsq+wsq), fmaf(-2,...)
__device__ __forceinline__ float exact_dist(const float* hv, float hs,
                                            const float* __restrict__ w,
                                            float wsqc, int c) {
  const float* wr = w + (size_t)c * E;
  float dot = 0.f;
#pragma unroll
  for (int k = 0; k < E; ++k) dot = fmaf(wr[k], hv[k], dot);
  return fmaf(-2.f, dot, hs + wsqc);
}

__device__ __forceinline__ unsigned short bf16_rn(float f) {
  unsigned int u = __float_as_uint(f);
  u += 0x7FFFu + ((u >> 16) & 1u);
  return (unsigned short)(u >> 16);
}
__device__ __forceinline__ float bf16_to_f(unsigned short s) {
  return __uint_as_float(((unsigned int)s) << 16);
}

// ---------- fused prep: blocks 0..15 -> w path, 16..271 -> x path ----------
__global__ __launch_bounds__(256) void prep_kernel(
    const float* __restrict__ w, const float* __restrict__ x,
    float* __restrict__ wsq, float* __restrict__ hsq,
    short* __restrict__ whiS, short* __restrict__ wloS,
    int* __restrict__ ovfCnt) {
  if (blockIdx.x < 16) {
    const int q = blockIdx.x * 256 + threadIdx.x;
    if (q == 0) *ovfCnt = 0;
    float v[E];
    load_row64(w + (size_t)q * E, v);
    wsq[q] = pairwise_sq_sum64(v);
    const int T = q >> 6, code_in = q & 63;
#pragma unroll
    for (int ch = 0; ch < 8; ++ch) {
      s8v hi, lo;
#pragma unroll
      for (int j = 0; j < 8; ++j) {
        const float f = v[ch * 8 + j];
        const unsigned short h = bf16_rn(f);
        const float resid = f - bf16_to_f(h);
        hi[j] = (short)h;
        lo[j] = (short)bf16_rn(resid);
      }
      const size_t base = (size_t)T * 4096 + ((size_t)(ch * 64 + code_in)) * 8;
      *(s8v*)&whiS[base] = hi;
      *(s8v*)&wloS[base] = lo;
    }
  } else {
    const int n = (blockIdx.x - 16) * 256 + threadIdx.x;
    float v[E];
    load_row64(x + (size_t)n * E, v);
    hsq[n] = pairwise_sq_sum64(v);
  }
}

// ---------- main: MFMA screen, SW-pipelined staging (1 barrier/ts) ----------
__global__ __launch_bounds__(256, 2) void dist_kernel(
    const float* __restrict__ x, const short* __restrict__ whiS,
    const short* __restrict__ wloS, const float* __restrict__ wsq,
    const float* __restrict__ hsq, const float* __restrict__ w,
    float* __restrict__ out, int* __restrict__ ovfCnt,
    int* __restrict__ ovfRows) {
  __shared__ short BsHi[2][CT * 64];   // 2 x 8 KB (double-buffered)
  __shared__ short BsLo[2][CT * 64];   // 2 x 8 KB
  __shared__ float WsS[2][CT];
  __shared__ int cnt[128];
  __shared__ int flagS[128];
  __shared__ int lists[128][CAP_LIST];
  __shared__ int bestRow[128];

  const int tid = threadIdx.x;
  const int wv = tid >> 6;
  const int lane = tid & 63;
  const int n = lane & 15;
  const int quad = lane >> 4;
  const int rowBase = blockIdx.x * 128;

  if (tid < 128) {
    cnt[tid] = 0;
    flagS[tid] = 0;
  }

  // ---- A-frags: a = -2x, split hi/lo, built once ----
  s8v ahi[2][2], alo[2][2];  // [rowtile][ks]
#pragma unroll
  for (int rt = 0; rt < 2; ++rt) {
#pragma unroll
    for (int ks = 0; ks < 2; ++ks) {
      const int gRow = rowBase + wv * 32 + rt * 16 + n;
      const float* xp = x + (size_t)gRow * E + ks * 32 + quad * 8;
      const float4 v0 = ((const float4*)xp)[0];
      const float4 v1 = ((const float4*)xp)[1];
      float vals[8] = {v0.x, v0.y, v0.z, v0.w, v1.x, v1.y, v1.z, v1.w};
      s8v hi, lo;
#pragma unroll
      for (int j = 0; j < 8; ++j) {
        const float a = -2.f * vals[j];
        const unsigned short h = bf16_rn(a);
        hi[j] = (short)h;
        lo[j] = (short)bf16_rn(a - bf16_to_f(h));
      }
      ahi[rt][ks] = hi;
      alo[rt][ks] = lo;
    }
  }

  // hsq + 4.0 offset folded into C-init (keeps packed floats positive)
  float hsqv4[2][4];
#pragma unroll
  for (int rt = 0; rt < 2; ++rt)
#pragma unroll
    for (int r = 0; r < 4; ++r)
      hsqv4[rt][r] = hsq[rowBase + wv * 32 + rt * 16 + quad * 4 + r] + 4.0f;

  // branchless packed top-2 per (rowtile, r): key = (bits(d+4)&KMASK)|code
  unsigned int m0[2][4], m1[2][4];
#pragma unroll
  for (int rt = 0; rt < 2; ++rt)
#pragma unroll
    for (int r = 0; r < 4; ++r) {
      m0[rt][r] = 0xFFFFFFFFu;
      m1[rt][r] = 0xFFFFFFFFu;
    }

  // ---- prefetch ts=0 into registers ----
  int4 pH0, pH1, pL0, pL1;
  float pW;
  {
    const int4* gh = (const int4*)whiS;
    const int4* gl = (const int4*)wloS;
    pH0 = gh[tid];
    pH1 = gh[tid + 256];
    pL0 = gl[tid];
    pL1 = gl[tid + 256];
    pW = (tid < CT) ? wsq[tid] : 0.f;
  }

#pragma unroll 1
  for (int ts = 0; ts < NTS; ++ts) {
    const int buf = ts & 1;
    // ---- write prefetched tile to LDS (vmcnt wait lands here, long ago) ----
    ((int4*)&BsHi[buf][0])[tid] = pH0;
    ((int4*)&BsHi[buf][0])[tid + 256] = pH1;
    ((int4*)&BsLo[buf][0])[tid] = pL0;
    ((int4*)&BsLo[buf][0])[tid + 256] = pL1;
    if (tid < CT) WsS[buf][tid] = pW;
    __syncthreads();  // single barrier per ts
    // ---- issue prefetch for ts+1 (in flight during compute below) ----
    if (ts + 1 < NTS) {
      const int4* gh = (const int4*)(whiS + (size_t)(ts + 1) * 4096);
      const int4* gl = (const int4*)(wloS + (size_t)(ts + 1) * 4096);
      pH0 = gh[tid];
      pH1 = gh[tid + 256];
      pL0 = gl[tid];
      pL1 = gl[tid + 256];
      if (tid < CT) pW = wsq[(ts + 1) * CT + tid];
    }

#pragma unroll
    for (int ct = 0; ct < 4; ++ct) {
      const s8v bhi0 = *(const s8v*)&BsHi[buf][(size_t)((0 * 4 + quad) * 64 + ct * 16 + n) * 8];
      const s8v bhi1 = *(const s8v*)&BsHi[buf][(size_t)((1 * 4 + quad) * 64 + ct * 16 + n) * 8];
      const s8v blo0 = *(const s8v*)&BsLo[buf][(size_t)((0 * 4 + quad) * 64 + ct * 16 + n) * 8];
      const s8v blo1 = *(const s8v*)&BsLo[buf][(size_t)((1 * 4 + quad) * 64 + ct * 16 + n) * 8];
      const float wsn = WsS[buf][ct * 16 + n];
      const unsigned int codeT = (unsigned int)(ts * CT + ct * 16 + n);
#pragma unroll
      for (int rt = 0; rt < 2; ++rt) {
        f4v acc;
        acc[0] = hsqv4[rt][0] + wsn;
        acc[1] = hsqv4[rt][1] + wsn;
        acc[2] = hsqv4[rt][2] + wsn;
        acc[3] = hsqv4[rt][3] + wsn;
        acc = __builtin_amdgcn_mfma_f32_16x16x32_bf16(alo[rt][0], bhi0, acc, 0, 0, 0);
        acc = __builtin_amdgcn_mfma_f32_16x16x32_bf16(ahi[rt][0], blo0, acc, 0, 0, 0);
        acc = __builtin_amdgcn_mfma_f32_16x16x32_bf16(ahi[rt][0], bhi0, acc, 0, 0, 0);
        acc = __builtin_amdgcn_mfma_f32_16x16x32_bf16(alo[rt][1], bhi1, acc, 0, 0, 0);
        acc = __builtin_amdgcn_mfma_f32_16x16x32_bf16(ahi[rt][1], blo1, acc, 0, 0, 0);
        acc = __builtin_amdgcn_mfma_f32_16x16x32_bf16(ahi[rt][1], bhi1, acc, 0, 0, 0);
#pragma unroll
        for (int r = 0; r < 4; ++r) {
          const unsigned int key =
              (__float_as_uint(acc[r]) & KMASK) | codeT;      // v_and_or_b32
          const unsigned int lo = m0[rt][r] < key ? m0[rt][r] : key;  // v_min
          const unsigned int hi = m0[rt][r] > key ? m0[rt][r] : key;  // v_max
          m0[rt][r] = lo;
          m1[rt][r] = m1[rt][r] < hi ? m1[rt][r] : hi;                // v_min
        }
      }
    }
  }

  // ---- candidate collection: rowmin via 16-lane butterfly, push <= thr ----
  __syncthreads();
#pragma unroll
  for (int rt = 0; rt < 2; ++rt) {
#pragma unroll
    for (int r = 0; r < 4; ++r) {
      unsigned int km = m0[rt][r];
#pragma unroll
      for (int off = 1; off < 16; off <<= 1) {
        const unsigned int o = __shfl_xor(km, off, 64);
        km = o < km ? o : km;
      }
      const float thr = __uint_as_float(km & KMASK) + MARGIN;
      const int row_l = wv * 32 + rt * 16 + quad * 4 + r;
      const float f0 = __uint_as_float(m0[rt][r] & KMASK);
      const float f1 = __uint_as_float(m1[rt][r] & KMASK);
      if (f0 <= thr) {
        const int pos = atomicAdd(&cnt[row_l], 1);
        if (pos < CAP_LIST) lists[row_l][pos] = (int)(m0[rt][r] & 0xFFFu);
        else flagS[row_l] = 1;
      }
      if (f1 <= thr) flagS[row_l] = 1;  // a dropped 3rd could be in-margin
    }
  }
  __syncthreads();

  // ---- exact recheck (reference-bitwise) over candidates ----
  if (tid < 128) {
    const int g = rowBase + tid;
    if (flagS[tid]) {
      const int pos = atomicAdd(ovfCnt, 1);
      ovfRows[pos] = g;
    } else {
      float hv[E];
      load_row64(x + (size_t)g * E, hv);
      const float hs = hsq[g];
      const int nc = cnt[tid] < CAP_LIST ? cnt[tid] : CAP_LIST;
      float bd = INFINITY;
      int bi = 0x7FFFFFFF;
      for (int i = 0; i < nc; ++i) {
        const int c = lists[tid][i];
        const float d = exact_dist(hv, hs, w, wsq[c], c);
        if (d < bd || (d == bd && c < bi)) { bd = d; bi = c; }
      }
      bestRow[tid] = bi;
      out[(size_t)N_ROWS * E + g] = (float)bi;
    }
  }
  __syncthreads();
  // ---- gather codeword ----
  {
    const int r = tid >> 1, h = tid & 1;
    if (!flagS[r]) {
      const int bi = bestRow[r];
      const float4* src = (const float4*)(w + (size_t)bi * E + h * 32);
      float4* dst = (float4*)(out + (size_t)(rowBase + r) * E + h * 32);
#pragma unroll
      for (int i = 0; i < 8; ++i) dst[i] = src[i];
    }
  }
}

// ---------- fallback: full exact scan, wave/row, no per-lane arrays ----------
// row is wave-uniform -> h loads become s_load; each lane runs 4 concurrent
// k-ascending fmaf chains (bit-identical dot order to reference BLAS chain).
__global__ __launch_bounds__(256) void fallback_kernel(
    const float* __restrict__ x, const float* __restrict__ w,
    const float* __restrict__ wsq, const float* __restrict__ hsq,
    float* __restrict__ out, const int* __restrict__ ovfCnt,
    const int* __restrict__ ovfRows) {
  const int novf = *ovfCnt;
  const int lane = threadIdx.x & 63;
  const int gw = blockIdx.x * 4 + (threadIdx.x >> 6);  // global wave id, 4096
  for (int i = gw; i < novf; i += 4096) {
    const int row = __builtin_amdgcn_readfirstlane(ovfRows[i]);
    const float* hvp = x + (size_t)row * E;  // wave-uniform base
    const float hs = hsq[row];
    float bd = INFINITY;
    int bi = 0x7FFFFFFF;
    for (int c0 = 0; c0 < 16; ++c0) {
      const int cb = c0 * 256;
      const float* w0 = w + (size_t)(cb + 0 * 64 + lane) * E;
      const float* w1 = w + (size_t)(cb + 1 * 64 + lane) * E;
      const float* w2 = w + (size_t)(cb + 2 * 64 + lane) * E;
      const float* w3 = w + (size_t)(cb + 3 * 64 + lane) * E;
      float a0 = 0.f, a1 = 0.f, a2 = 0.f, a3 = 0.f;
#pragma unroll
      for (int k4 = 0; k4 < 16; ++k4) {
        const float4 hk = *(const float4*)(hvp + k4 * 4);  // s_load (uniform)
        const float4 q0 = *(const float4*)(w0 + k4 * 4);
        const float4 q1 = *(const float4*)(w1 + k4 * 4);
        const float4 q2 = *(const float4*)(w2 + k4 * 4);
        const float4 q3 = *(const float4*)(w3 + k4 * 4);
        a0 = fmaf(q0.x, hk.x, a0); a0 = fmaf(q0.y, hk.y, a0);
        a0 = fmaf(q0.z, hk.z, a0); a0 = fmaf(q0.w, hk.w, a0);
        a1 = fmaf(q1.x, hk.x, a1); a1 = fmaf(q1.y, hk.y, a1);
        a1 = fmaf(q1.z, hk.z, a1); a1 = fmaf(q1.w, hk.w, a1);
        a2 = fmaf(q2.x, hk.x, a2); a2 = fmaf(q2.y, hk.y, a2);
        a2 = fmaf(q2.z, hk.z, a2); a2 = fmaf(q2.w, hk.w, a2);
        a3 = fmaf(q3.x, hk.x, a3); a3 = fmaf(q3.y, hk.y, a3);
        a3 = fmaf(q3.z, hk.z, a3); a3 = fmaf(q3.w, hk.w, a3);
      }
      {
        const int c = cb + lane;
        const float d = fmaf(-2.f, a0, hs + wsq[c]);
        if (d < bd || (d == bd && c < bi)) { bd = d; bi = c; }
      }
      {
        const int c = cb + 64 + lane;
        const float d = fmaf(-2.f, a1, hs + wsq[c]);
        if (d < bd || (d == bd && c < bi)) { bd = d; bi = c; }
      }
      {
        const int c = cb + 128 + lane;
        const float d = fmaf(-2.f, a2, hs + wsq[c]);
        if (d < bd || (d == bd && c < bi)) { bd = d; bi = c; }
      }
      {
        const int c = cb + 192 + lane;
        const float d = fmaf(-2.f, a3, hs + wsq[c]);
        if (d < bd || (d == bd && c < bi)) { bd = d; bi = c; }
      }
    }
#pragma unroll
    for (int off = 1; off < 64; off <<= 1) {
      const float od = __shfl_xor(bd, off, 64);
      const int oi = __shfl_xor(bi, off, 64);
      if (od < bd || (od == bd && oi < bi)) { bd = od; bi = oi; }
    }
    if (lane == 0) out[(size_t)N_ROWS * E + row] = (float)bi;
    out[(size_t)row * E + lane] = w[(size_t)bi * E + lane];
  }
}

extern "C" void kernel_launch(void* const* d_in, const int* in_sizes, int n_in,
                              void* d_out, int out_size, void* d_ws,
                              size_t ws_size, hipStream_t stream) {
  const float* x = (const float*)d_in[0];
  const float* w = (const float*)d_in[1];
  float* out = (float*)d_out;

  float* wsq = (float*)d_ws;
  float* hsq = wsq + Q;
  short* whiS = (short*)(hsq + N_ROWS);
  short* wloS = whiS + (size_t)Q * E;
  int* ovfCnt = (int*)(wloS + (size_t)Q * E);
  int* ovfRows = ovfCnt + 4;

  prep_kernel<<<272, 256, 0, stream>>>(w, x, wsq, hsq, whiS, wloS, ovfCnt);
  dist_kernel<<<N_ROWS / 128, 256, 0, stream>>>(x, whiS, wloS, wsq, hsq, w, out,
                                                ovfCnt, ovfRows);
  fallback_kernel<<<1024, 256, 0, stream>>>(x, w, wsq, hsq, out, ovfCnt,
                                            ovfRows);
}

// Round 8
// 192.438 us; speedup vs baseline: 1.6774x; 1.5735x over previous
//
#include <hip/hip_runtime.h>
#include <math.h>

#define N_ROWS 65536
#define Q 4096
#define E 64
#define CT 64                 // codes staged per tile-step
#define NTS (Q / CT)          // 64 tile-steps
#define MARGIN 0.25f
#define CAP_LIST 8
#define KMASK 0xFFFFF000u

typedef short s8v __attribute__((ext_vector_type(8)));   // 8 bf16 (4 VGPRs)
typedef float f4v __attribute__((ext_vector_type(4)));   // 4 fp32 acc

// ---------- exact-arithmetic helpers (validated absmax=0 rounds 1-7) ----------
__device__ __forceinline__ float pairwise_sq_sum64(const float* v) {
#pragma clang fp contract(off)
  float r[8];
#pragma unroll
  for (int j = 0; j < 8; ++j) r[j] = v[j] * v[j];
#pragma unroll
  for (int i = 8; i < 64; i += 8) {
#pragma unroll
    for (int j = 0; j < 8; ++j) {
      float p = v[i + j] * v[i + j];
      r[j] = r[j] + p;
    }
  }
  return ((r[0] + r[1]) + (r[2] + r[3])) + ((r[4] + r[5]) + (r[6] + r[7]));
}

__device__ __forceinline__ void load_row64(const float* __restrict__ src,
                                           float* dst) {
  const float4* p = (const float4*)src;
#pragma unroll
  for (int k4 = 0; k4 < 16; ++k4) {
    const float4 t = p[k4];
    dst[4 * k4 + 0] = t.x;
    dst[4 * k4 + 1] = t.y;
    dst[4 * k4 + 2] = t.z;
    dst[4 * k4 + 3] = t.w;
  }
}

// exact distance, reference-bitwise: sequential fmaf k ascending,
// RN(hsq+wsq), fmaf(-2,...)
__device__ __forceinline__ float exact_dist(const float* hv, float hs,
                                            const float* __restrict__ w,
                                            float wsqc, int c) {
  const float* wr = w + (size_t)c * E;
  float dot = 0.f;
#pragma unroll
  for (int k = 0; k < E; ++k) dot = fmaf(wr[k], hv[k], dot);
  return fmaf(-2.f, dot, hs + wsqc);
}

__device__ __forceinline__ unsigned short bf16_rn(float f) {
  unsigned int u = __float_as_uint(f);
  u += 0x7FFFu + ((u >> 16) & 1u);
  return (unsigned short)(u >> 16);
}
__device__ __forceinline__ float bf16_to_f(unsigned short s) {
  return __uint_as_float(((unsigned int)s) << 16);
}

// ---------- fused prep: blocks 0..15 -> w path (+wT), 16..271 -> x path ------
__global__ __launch_bounds__(256) void prep_kernel(
    const float* __restrict__ w, const float* __restrict__ x,
    float* __restrict__ wsq, float* __restrict__ hsq,
    short* __restrict__ whiS, short* __restrict__ wloS,
    float* __restrict__ wT, int* __restrict__ ovfCnt) {
  if (blockIdx.x < 16) {
    const int q = blockIdx.x * 256 + threadIdx.x;
    if (q == 0) *ovfCnt = 0;
    float v[E];
    load_row64(w + (size_t)q * E, v);
    wsq[q] = pairwise_sq_sum64(v);
    // transposed copy (coalesced stores across q)
#pragma unroll
    for (int k = 0; k < E; ++k) wT[(size_t)k * Q + q] = v[k];
    const int T = q >> 6, code_in = q & 63;
#pragma unroll
    for (int ch = 0; ch < 8; ++ch) {
      s8v hi, lo;
#pragma unroll
      for (int j = 0; j < 8; ++j) {
        const float f = v[ch * 8 + j];
        const unsigned short h = bf16_rn(f);
        const float resid = f - bf16_to_f(h);
        hi[j] = (short)h;
        lo[j] = (short)bf16_rn(resid);
      }
      const size_t base = (size_t)T * 4096 + ((size_t)(ch * 64 + code_in)) * 8;
      *(s8v*)&whiS[base] = hi;
      *(s8v*)&wloS[base] = lo;
    }
  } else {
    const int n = (blockIdx.x - 16) * 256 + threadIdx.x;
    float v[E];
    load_row64(x + (size_t)n * E, v);
    hsq[n] = pairwise_sq_sum64(v);
  }
}

// ---------- main: MFMA screen, SW-pipelined, branchless packed top-3 ---------
__global__ __launch_bounds__(256, 2) void dist_kernel(
    const float* __restrict__ x, const short* __restrict__ whiS,
    const short* __restrict__ wloS, const float* __restrict__ wsq,
    const float* __restrict__ hsq, const float* __restrict__ w,
    float* __restrict__ out, int* __restrict__ ovfCnt,
    int* __restrict__ ovfRows) {
  __shared__ short BsHi[2][CT * 64];   // 2 x 8 KB (double-buffered)
  __shared__ short BsLo[2][CT * 64];   // 2 x 8 KB
  __shared__ float WsS[2][CT];
  __shared__ int cnt[128];
  __shared__ int flagS[128];
  __shared__ int lists[128][CAP_LIST];
  __shared__ int bestRow[128];

  const int tid = threadIdx.x;
  const int wv = tid >> 6;
  const int lane = tid & 63;
  const int n = lane & 15;
  const int quad = lane >> 4;
  const int rowBase = blockIdx.x * 128;

  if (tid < 128) {
    cnt[tid] = 0;
    flagS[tid] = 0;
  }

  // ---- A-frags: a = -2x, split hi/lo, built once ----
  s8v ahi[2][2], alo[2][2];  // [rowtile][ks]
#pragma unroll
  for (int rt = 0; rt < 2; ++rt) {
#pragma unroll
    for (int ks = 0; ks < 2; ++ks) {
      const int gRow = rowBase + wv * 32 + rt * 16 + n;
      const float* xp = x + (size_t)gRow * E + ks * 32 + quad * 8;
      const float4 v0 = ((const float4*)xp)[0];
      const float4 v1 = ((const float4*)xp)[1];
      float vals[8] = {v0.x, v0.y, v0.z, v0.w, v1.x, v1.y, v1.z, v1.w};
      s8v hi, lo;
#pragma unroll
      for (int j = 0; j < 8; ++j) {
        const float a = -2.f * vals[j];
        const unsigned short h = bf16_rn(a);
        hi[j] = (short)h;
        lo[j] = (short)bf16_rn(a - bf16_to_f(h));
      }
      ahi[rt][ks] = hi;
      alo[rt][ks] = lo;
    }
  }

  // hsq + 4.0 offset folded into C-init (keeps packed floats positive)
  float hsqv4[2][4];
#pragma unroll
  for (int rt = 0; rt < 2; ++rt)
#pragma unroll
    for (int r = 0; r < 4; ++r)
      hsqv4[rt][r] = hsq[rowBase + wv * 32 + rt * 16 + quad * 4 + r] + 4.0f;

  // branchless packed top-3 per (rowtile, r): key = (bits(d+4)&KMASK)|code
  unsigned int m0[2][4], m1[2][4], m2[2][4];
#pragma unroll
  for (int rt = 0; rt < 2; ++rt)
#pragma unroll
    for (int r = 0; r < 4; ++r) {
      m0[rt][r] = 0xFFFFFFFFu;
      m1[rt][r] = 0xFFFFFFFFu;
      m2[rt][r] = 0xFFFFFFFFu;
    }

  // ---- prefetch ts=0 into registers ----
  int4 pH0, pH1, pL0, pL1;
  float pW;
  {
    const int4* gh = (const int4*)whiS;
    const int4* gl = (const int4*)wloS;
    pH0 = gh[tid];
    pH1 = gh[tid + 256];
    pL0 = gl[tid];
    pL1 = gl[tid + 256];
    pW = (tid < CT) ? wsq[tid] : 0.f;
  }

#pragma unroll 1
  for (int ts = 0; ts < NTS; ++ts) {
    const int buf = ts & 1;
    ((int4*)&BsHi[buf][0])[tid] = pH0;
    ((int4*)&BsHi[buf][0])[tid + 256] = pH1;
    ((int4*)&BsLo[buf][0])[tid] = pL0;
    ((int4*)&BsLo[buf][0])[tid + 256] = pL1;
    if (tid < CT) WsS[buf][tid] = pW;
    __syncthreads();  // single barrier per ts
    if (ts + 1 < NTS) {
      const int4* gh = (const int4*)(whiS + (size_t)(ts + 1) * 4096);
      const int4* gl = (const int4*)(wloS + (size_t)(ts + 1) * 4096);
      pH0 = gh[tid];
      pH1 = gh[tid + 256];
      pL0 = gl[tid];
      pL1 = gl[tid + 256];
      if (tid < CT) pW = wsq[(ts + 1) * CT + tid];
    }

#pragma unroll
    for (int ct = 0; ct < 4; ++ct) {
      const s8v bhi0 = *(const s8v*)&BsHi[buf][(size_t)((0 * 4 + quad) * 64 + ct * 16 + n) * 8];
      const s8v bhi1 = *(const s8v*)&BsHi[buf][(size_t)((1 * 4 + quad) * 64 + ct * 16 + n) * 8];
      const s8v blo0 = *(const s8v*)&BsLo[buf][(size_t)((0 * 4 + quad) * 64 + ct * 16 + n) * 8];
      const s8v blo1 = *(const s8v*)&BsLo[buf][(size_t)((1 * 4 + quad) * 64 + ct * 16 + n) * 8];
      const float wsn = WsS[buf][ct * 16 + n];
      const unsigned int codeT = (unsigned int)(ts * CT + ct * 16 + n);
#pragma unroll
      for (int rt = 0; rt < 2; ++rt) {
        f4v acc;
        acc[0] = hsqv4[rt][0] + wsn;
        acc[1] = hsqv4[rt][1] + wsn;
        acc[2] = hsqv4[rt][2] + wsn;
        acc[3] = hsqv4[rt][3] + wsn;
        acc = __builtin_amdgcn_mfma_f32_16x16x32_bf16(alo[rt][0], bhi0, acc, 0, 0, 0);
        acc = __builtin_amdgcn_mfma_f32_16x16x32_bf16(ahi[rt][0], blo0, acc, 0, 0, 0);
        acc = __builtin_amdgcn_mfma_f32_16x16x32_bf16(ahi[rt][0], bhi0, acc, 0, 0, 0);
        acc = __builtin_amdgcn_mfma_f32_16x16x32_bf16(alo[rt][1], bhi1, acc, 0, 0, 0);
        acc = __builtin_amdgcn_mfma_f32_16x16x32_bf16(ahi[rt][1], blo1, acc, 0, 0, 0);
        acc = __builtin_amdgcn_mfma_f32_16x16x32_bf16(ahi[rt][1], bhi1, acc, 0, 0, 0);
#pragma unroll
        for (int r = 0; r < 4; ++r) {
          const unsigned int key =
              (__float_as_uint(acc[r]) & KMASK) | codeT;       // v_and_or_b32
          // branchless 3-deep insertion: keeps m0 <= m1 <= m2
          const unsigned int a = m0[rt][r] < key ? m0[rt][r] : key;  // min
          const unsigned int b = m0[rt][r] > key ? m0[rt][r] : key;  // max
          m0[rt][r] = a;
          const unsigned int c = m1[rt][r] < b ? m1[rt][r] : b;      // min
          const unsigned int d = m1[rt][r] > b ? m1[rt][r] : b;      // max
          m1[rt][r] = c;
          m2[rt][r] = m2[rt][r] < d ? m2[rt][r] : d;                 // min
        }
      }
    }
  }

  // ---- candidate collection: rowmin via 16-lane butterfly, push <= thr ----
  __syncthreads();
#pragma unroll
  for (int rt = 0; rt < 2; ++rt) {
#pragma unroll
    for (int r = 0; r < 4; ++r) {
      unsigned int km = m0[rt][r];
#pragma unroll
      for (int off = 1; off < 16; off <<= 1) {
        const unsigned int o = __shfl_xor(km, off, 64);
        km = o < km ? o : km;
      }
      const float thr = __uint_as_float(km & KMASK) + MARGIN;
      const int row_l = wv * 32 + rt * 16 + quad * 4 + r;
      const float f0 = __uint_as_float(m0[rt][r] & KMASK);
      const float f1 = __uint_as_float(m1[rt][r] & KMASK);
      const float f2 = __uint_as_float(m2[rt][r] & KMASK);
      if (f0 <= thr) {
        const int pos = atomicAdd(&cnt[row_l], 1);
        if (pos < CAP_LIST) lists[row_l][pos] = (int)(m0[rt][r] & 0xFFFu);
        else flagS[row_l] = 1;
      }
      if (f1 <= thr) {
        const int pos = atomicAdd(&cnt[row_l], 1);
        if (pos < CAP_LIST) lists[row_l][pos] = (int)(m1[rt][r] & 0xFFFu);
        else flagS[row_l] = 1;
      }
      if (f2 <= thr) flagS[row_l] = 1;  // a dropped 4th could be in-margin
    }
  }
  __syncthreads();

  // ---- exact recheck (reference-bitwise) over candidates ----
  if (tid < 128) {
    const int g = rowBase + tid;
    if (flagS[tid]) {
      const int pos = atomicAdd(ovfCnt, 1);
      ovfRows[pos] = g;
    } else {
      float hv[E];
      load_row64(x + (size_t)g * E, hv);
      const float hs = hsq[g];
      const int nc = cnt[tid] < CAP_LIST ? cnt[tid] : CAP_LIST;
      float bd = INFINITY;
      int bi = 0x7FFFFFFF;
      for (int i = 0; i < nc; ++i) {
        const int c = lists[tid][i];
        const float d = exact_dist(hv, hs, w, wsq[c], c);
        if (d < bd || (d == bd && c < bi)) { bd = d; bi = c; }
      }
      bestRow[tid] = bi;
      out[(size_t)N_ROWS * E + g] = (float)bi;
    }
  }
  __syncthreads();
  // ---- gather codeword ----
  {
    const int r = tid >> 1, h = tid & 1;
    if (!flagS[r]) {
      const int bi = bestRow[r];
      const float4* src = (const float4*)(w + (size_t)bi * E + h * 32);
      float4* dst = (float4*)(out + (size_t)(rowBase + r) * E + h * 32);
#pragma unroll
      for (int i = 0; i < 8; ++i) dst[i] = src[i];
    }
  }
}

// ---------- fallback: block-per-row, coalesced via wT, exact bitwise ---------
__global__ __launch_bounds__(256) void fallback_kernel(
    const float* __restrict__ x, const float* __restrict__ wT,
    const float* __restrict__ w, const float* __restrict__ wsq,
    const float* __restrict__ hsq, float* __restrict__ out,
    const int* __restrict__ ovfCnt, const int* __restrict__ ovfRows) {
  __shared__ float xs[E];
  __shared__ float redD[4];
  __shared__ int redI[4];
  __shared__ int bestS;
  const int tid = threadIdx.x;
  const int lane = tid & 63;
  const int wvi = tid >> 6;
  const int novf = *ovfCnt;

  for (int i = blockIdx.x; i < novf; i += gridDim.x) {
    const int row = ovfRows[i];
    if (tid < 16)
      *(float4*)&xs[tid * 4] = *(const float4*)(x + (size_t)row * E + tid * 4);
    __syncthreads();
    const float hs = hsq[row];
    float bd = INFINITY;
    int bi = 0x7FFFFFFF;
#pragma unroll 1
    for (int cc = 0; cc < 16; ++cc) {
      const int c = cc * 256 + tid;
      float dot = 0.f;
#pragma unroll
      for (int k = 0; k < E; ++k)
        dot = fmaf(wT[(size_t)k * Q + c], xs[k], dot);  // lane-contiguous
      const float d = fmaf(-2.f, dot, hs + wsq[c]);
      if (d < bd || (d == bd && c < bi)) { bd = d; bi = c; }
    }
    // wave reduce (lexicographic (d, c))
#pragma unroll
    for (int off = 1; off < 64; off <<= 1) {
      const float od = __shfl_xor(bd, off, 64);
      const int oi = __shfl_xor(bi, off, 64);
      if (od < bd || (od == bd && oi < bi)) { bd = od; bi = oi; }
    }
    if (lane == 0) { redD[wvi] = bd; redI[wvi] = bi; }
    __syncthreads();
    if (tid == 0) {
      float fb = redD[0];
      int fi = redI[0];
#pragma unroll
      for (int t = 1; t < 4; ++t) {
        if (redD[t] < fb || (redD[t] == fb && redI[t] < fi)) {
          fb = redD[t];
          fi = redI[t];
        }
      }
      bestS = fi;
      out[(size_t)N_ROWS * E + row] = (float)fi;
    }
    __syncthreads();
    if (tid < 16) {
      const int bi2 = bestS;
      *(float4*)(out + (size_t)row * E + tid * 4) =
          *(const float4*)(w + (size_t)bi2 * E + tid * 4);
    }
    __syncthreads();  // xs/bestS reuse safety for next row
  }
}

extern "C" void kernel_launch(void* const* d_in, const int* in_sizes, int n_in,
                              void* d_out, int out_size, void* d_ws,
                              size_t ws_size, hipStream_t stream) {
  const float* x = (const float*)d_in[0];
  const float* w = (const float*)d_in[1];
  float* out = (float*)d_out;

  // ws: wsq[4096] | hsq[65536] | whiS[262144] s16 | wloS[262144] s16
  //   | wT[262144] f32 | ovfCnt | pad | ovfRows[65536]   (~2.6 MB)
  float* wsq = (float*)d_ws;
  float* hsq = wsq + Q;
  short* whiS = (short*)(hsq + N_ROWS);
  short* wloS = whiS + (size_t)Q * E;
  float* wT = (float*)(wloS + (size_t)Q * E);
  int* ovfCnt = (int*)(wT + (size_t)Q * E);
  int* ovfRows = ovfCnt + 4;

  prep_kernel<<<272, 256, 0, stream>>>(w, x, wsq, hsq, whiS, wloS, wT, ovfCnt);
  dist_kernel<<<N_ROWS / 128, 256, 0, stream>>>(x, whiS, wloS, wsq, hsq, w, out,
                                                ovfCnt, ovfRows);
  fallback_kernel<<<512, 256, 0, stream>>>(x, wT, w, wsq, hsq, out, ovfCnt,
                                           ovfRows);
}